// Round 6
// baseline (101.648 us; speedup 1.0000x reference)
//
#include <hip/hip_runtime.h>
#include <math.h>

#define TT 128
#define IN_CH 32
#define NPATH 256
#define SIGCH 7380
#define K1 29520
#define N1 512
#define N2 256
#define BK1 12

// ---------------- Kernel 1: conv + time-augment + depth-4 signature ----------------
// One block per path. After staging dx into LDS, each of 243 threads owns 3
// triples (i1,i2,i3..i3+2) sharing (i1,i2) and maintains its OWN running
// S1[i1], S2[i1i2], S3[triple] scalars -> no barriers, no cross-thread deps.
// Output written TRANSPOSED: sigT[k][b] (k = oc*7380+ch, b = batch row) so
// gemm1 can read 16 consecutive rows as one 64B line via scalar loads.
__global__ __launch_bounds__(256, 1) void sig_kernel(const float* __restrict__ x,
        const float* __restrict__ cw, const float* __restrict__ cb,
        float* __restrict__ sigT /*[29520][64]*/) {
    __shared__ float inc[TT][12];
    const int p = blockIdx.x;
    const int b = p >> 2, oc = p & 3;
    const int tid = threadIdx.x;

    const float4 wv = *(const float4*)(cw + oc * 4);
    const float bias = cb[oc];
    const float* xb = x + (long)b * TT * IN_CH;

    // dx staging (basepoint=True: first increment is y[0] itself)
    for (int it = tid; it < TT * 8; it += 256) {
        const int t = it >> 3, ch = it & 7;
        const float4 xa = *(const float4*)(xb + t * IN_CH + ch * 4);
        float v = xa.x * wv.x + xa.y * wv.y + xa.z * wv.z + xa.w * wv.w + bias;
        if (t > 0) {
            const float4 xm = *(const float4*)(xb + (t - 1) * IN_CH + ch * 4);
            v -= xm.x * wv.x + xm.y * wv.y + xm.z * wv.z + xm.w * wv.w + bias;
        }
        inc[t][1 + ch] = v;
    }
    for (int t = tid; t < TT; t += 256) inc[t][0] = t ? (1.f / 127.f) : 0.f;
    __syncthreads();

    if (tid >= 243) return;  // no barriers below

    const int base3 = 3 * tid;               // tr = base3 + q, q = 0..2
    const int i1 = base3 / 81;               // shared across q
    const int i2 = (base3 / 9) % 9;          // shared across q
    const int i30 = base3 % 9;               // i3 = i30 + q, stays < 9

    float S4[3][9] = {};
    float s3[3] = {0.f, 0.f, 0.f};
    float s2 = 0.f, s1 = 0.f;

    float4 A0 = *(const float4*)&inc[0][0];
    float4 A1 = *(const float4*)&inc[0][4];
    float A2 = inc[0][8];
    float e1 = inc[0][i1], e2 = inc[0][i2];
    float f0 = inc[0][i30], f1 = inc[0][i30 + 1], f2 = inc[0][i30 + 2];

#pragma unroll 2
    for (int t = 0; t < TT; ++t) {
        const int tn = (t + 1) & (TT - 1);
        const float4 nA0 = *(const float4*)&inc[tn][0];
        const float4 nA1 = *(const float4*)&inc[tn][4];
        const float nA2 = inc[tn][8];
        const float ne1 = inc[tn][i1], ne2 = inc[tn][i2];
        const float nf0 = inc[tn][i30], nf1 = inc[tn][i30 + 1], nf2 = inc[tn][i30 + 2];

        const float t12 = e1 * e2;
        const float s1d2 = s1 * e2;
        const float Ak = t12 * (1.f / 24.f) + s1d2 * (1.f / 6.f) + s2 * 0.5f;
        const float Bk = t12 * (1.f / 6.f) + s1d2 * 0.5f + s2;

        const float K0 = f0 * Ak + s3[0];
        const float K1v = f1 * Ak + s3[1];
        const float K2v = f2 * Ak + s3[2];

#define UPD(Q, KK) \
        S4[Q][0] += (KK) * A0.x; S4[Q][1] += (KK) * A0.y; \
        S4[Q][2] += (KK) * A0.z; S4[Q][3] += (KK) * A0.w; \
        S4[Q][4] += (KK) * A1.x; S4[Q][5] += (KK) * A1.y; \
        S4[Q][6] += (KK) * A1.z; S4[Q][7] += (KK) * A1.w; \
        S4[Q][8] += (KK) * A2;
        UPD(0, K0) UPD(1, K1v) UPD(2, K2v)
#undef UPD

        s3[0] += Bk * f0; s3[1] += Bk * f1; s3[2] += Bk * f2;
        s2 += e2 * (0.5f * e1 + s1);
        s1 += e1;

        A0 = nA0; A1 = nA1; A2 = nA2;
        e1 = ne1; e2 = ne2; f0 = nf0; f1 = nf1; f2 = nf2;
    }

    // transposed store: sigT[oc*SIGCH + ch][b]
    float* sp = sigT + (long)oc * SIGCH * 64 + b;
    if (i2 == 0 && i30 == 0) sp[(long)i1 * 64] = s1;
    if (i30 == 0) sp[(long)(9 + base3 / 9) * 64] = s2;
    sp[(long)(90 + base3 + 0) * 64] = s3[0];
    sp[(long)(90 + base3 + 1) * 64] = s3[1];
    sp[(long)(90 + base3 + 2) * 64] = s3[2];
#pragma unroll
    for (int q = 0; q < 3; q++)
#pragma unroll
        for (int l = 0; l < 9; l++)
            sp[(long)(819 + (base3 + q) * 9 + l) * 64] = S4[q][l];
}

// ---------------- Kernel 2: GEMM1 partials ----------------
// Block = 64 rows x 256 cols, 4 waves; wave w owns rows 16w..16w+15 (ALL its
// cols). The 16 z values per k are wave-uniform -> scalar s_load from sigT
// (SMEM pipe, zero LDS/VALU cost; one 64B line per k). w tile [12][256] in
// LDS, one contiguous conflict-free ds_read_b128 per lane per k.
// Reg-staged double buffer: next w tile loaded to regs during compute.
// Per k per wave: 128 VALU cyc vs ~12 LDS cyc -> VALU-bound.
__global__ __launch_bounds__(256, 2) void gemm1_kernel(const float* __restrict__ sigT,
        const float* __restrict__ w0, float* __restrict__ part, int KCH) {
    __shared__ float wt[BK1][256];
    const int nh = blockIdx.x;            // col half: 0/1
    const int kc = blockIdx.y;
    const int n0 = nh * 256, k0 = kc * KCH;
    const int tid = threadIdx.x;
    const int lane = tid & 63;
    const int wvid = __builtin_amdgcn_readfirstlane(tid >> 6);  // SGPR wave id
    const int r0 = wvid * 16;
    const int c4 = lane * 4;

    // prologue: stage tile 0 to regs
    float4 stg[3];
    {
        const float* ws0 = w0 + (long)k0 * N1 + n0;
#pragma unroll
        for (int i = 0; i < 3; i++) {
            const int q = tid + i * 256;
            stg[i] = *(const float4*)(ws0 + (long)(q >> 6) * N1 + (q & 63) * 4);
        }
    }

    float acc[16][4] = {};
    const float* zbase = sigT + r0;       // uniform: z[k][r0+i] = zbase[k*64+i]
    const int NT = KCH / BK1;

    for (int tile = 0; tile < NT; ++tile) {
        // commit staged regs to LDS
#pragma unroll
        for (int i = 0; i < 3; i++) {
            const int q = tid + i * 256;
            *(float4*)&wt[q >> 6][(q & 63) * 4] = stg[i];
        }
        __syncthreads();
        // issue next tile's global loads (latency hides under compute)
        if (tile + 1 < NT) {
            const float* ws2 = w0 + (long)(k0 + (tile + 1) * BK1) * N1 + n0;
#pragma unroll
            for (int i = 0; i < 3; i++) {
                const int q = tid + i * 256;
                stg[i] = *(const float4*)(ws2 + (long)(q >> 6) * N1 + (q & 63) * 4);
            }
        }
        const long kz = (long)(k0 + tile * BK1) * 64;
#pragma unroll 4
        for (int k = 0; k < BK1; ++k) {
            const float4* zp = (const float4*)(zbase + kz + (long)k * 64);
            const float4 za = zp[0], zb = zp[1], zc = zp[2], zd = zp[3];
            const float4 wf = *(const float4*)&wt[k][c4];
#define ROW(R, ZV) \
            acc[R][0] += (ZV) * wf.x; acc[R][1] += (ZV) * wf.y; \
            acc[R][2] += (ZV) * wf.z; acc[R][3] += (ZV) * wf.w;
            ROW(0, za.x) ROW(1, za.y) ROW(2, za.z) ROW(3, za.w)
            ROW(4, zb.x) ROW(5, zb.y) ROW(6, zb.z) ROW(7, zb.w)
            ROW(8, zc.x) ROW(9, zc.y) ROW(10, zc.z) ROW(11, zc.w)
            ROW(12, zd.x) ROW(13, zd.y) ROW(14, zd.z) ROW(15, zd.w)
#undef ROW
        }
        __syncthreads();
    }

    // write partial tile: part[kc][64][512]
    float* pp = part + ((long)kc * 64 + r0) * N1 + n0 + c4;
#pragma unroll
    for (int r = 0; r < 16; r++)
        *(float4*)(pp + (long)r * N1) =
            make_float4(acc[r][0], acc[r][1], acc[r][2], acc[r][3]);
}

// ---------------- Kernel 3: reduce partials + bias + sigmoid ----------------
__global__ __launch_bounds__(256) void red1_kernel(const float* __restrict__ part,
        const float* __restrict__ b0v, float* __restrict__ z1, int ksplit) {
    __shared__ float4 red[256];
    const int tid = threadIdx.x;
    const int g = tid & 31, s = tid >> 5;
    const int gg = blockIdx.x * 32 + g;           // float4 index in [0, 8192)
    const int per = (ksplit + 7) >> 3;
    const int ks = s * per, ke = min(ksplit, ks + per);
    float4 a = make_float4(0.f, 0.f, 0.f, 0.f);
    for (int kc = ks; kc < ke; kc++) {
        float4 pv = *(const float4*)(part + ((long)kc * 8192 + gg) * 4);
        a.x += pv.x; a.y += pv.y; a.z += pv.z; a.w += pv.w;
    }
    red[tid] = a;
    __syncthreads();
    if (tid < 128) { float4 o = red[tid + 128]; red[tid].x += o.x; red[tid].y += o.y; red[tid].z += o.z; red[tid].w += o.w; }
    __syncthreads();
    if (tid < 64) { float4 o = red[tid + 64]; red[tid].x += o.x; red[tid].y += o.y; red[tid].z += o.z; red[tid].w += o.w; }
    __syncthreads();
    if (tid < 32) {
        float4 sum = red[tid];
        float4 o = red[tid + 32];
        sum.x += o.x; sum.y += o.y; sum.z += o.z; sum.w += o.w;
        const float4 bv = *(const float4*)(b0v + (gg & 127) * 4);
        float4 r;
        r.x = 1.f / (1.f + expf(-(sum.x + bv.x)));
        r.y = 1.f / (1.f + expf(-(sum.y + bv.y)));
        r.z = 1.f / (1.f + expf(-(sum.z + bv.z)));
        r.w = 1.f / (1.f + expf(-(sum.w + bv.w)));
        *(float4*)(z1 + gg * 4) = r;
    }
}

// ---------------- Kernel 4: GEMM2 + bias + sigmoid (in-block K-split) ----------------
__global__ __launch_bounds__(256) void gemm2_kernel(const float* __restrict__ z1,
        const float* __restrict__ w1, const float* __restrict__ b1v,
        float* __restrict__ z2) {
    __shared__ float red[256];
    const int m = blockIdx.x >> 2, nq = blockIdx.x & 3;
    const int tid = threadIdx.x;
    const int c = tid & 63, s = tid >> 6;
    const int n = nq * 64 + c;
    const float* zr = z1 + m * N1 + s * 128;
    const float* wr = w1 + (long)(s * 128) * N2 + n;
    float acc = 0.f;
#pragma unroll 16
    for (int k = 0; k < 128; k++) acc += zr[k] * wr[(long)k * N2];
    red[tid] = acc;
    __syncthreads();
    if (tid < 128) red[tid] += red[tid + 128];
    __syncthreads();
    if (tid < 64) {
        float sum = red[tid] + red[tid + 64] + b1v[n];
        z2[m * N2 + n] = 1.f / (1.f + expf(-sum));
    }
}

// ---------------- Kernel 5: GEMM3 + log_softmax ----------------
__global__ __launch_bounds__(64) void head_kernel(const float* __restrict__ z2,
        const float* __restrict__ w2, const float* __restrict__ b2v,
        float* __restrict__ out) {
    const int m = blockIdx.x;
    const int tid = threadIdx.x;
    __shared__ float logits[10];
    if (tid < 10) {
        float s = b2v[tid];
        const float* zr = z2 + m * N2;
#pragma unroll 8
        for (int k = 0; k < N2; k++) s += zr[k] * w2[k * 10 + tid];
        logits[tid] = s;
    }
    __syncthreads();
    if (tid == 0) {
        float mx = logits[0];
        for (int j = 1; j < 10; j++) mx = fmaxf(mx, logits[j]);
        float sum = 0.f;
        for (int j = 0; j < 10; j++) sum += expf(logits[j] - mx);
        const float lse = mx + logf(sum);
        for (int j = 0; j < 10; j++) out[m * 10 + j] = logits[j] - lse;
    }
}

extern "C" void kernel_launch(void* const* d_in, const int* in_sizes, int n_in,
                              void* d_out, int out_size, void* d_ws, size_t ws_size,
                              hipStream_t stream) {
    const float* x  = (const float*)d_in[0];
    const float* cw = (const float*)d_in[1];
    const float* cb = (const float*)d_in[2];
    const float* w0 = (const float*)d_in[3];
    const float* b0 = (const float*)d_in[4];
    const float* w1 = (const float*)d_in[5];
    const float* b1 = (const float*)d_in[6];
    const float* w2 = (const float*)d_in[7];
    const float* b2 = (const float*)d_in[8];

    // tiered K-split by workspace: 29520 = ksplit * KCH, KCH % 12 == 0
    const size_t fixed = (size_t)NPATH * SIGCH + 64 * N1 + 64 * N2;
    int ksplit = 82, kch = 360;
    if (ws_size >= (fixed + (size_t)246 * 64 * N1) * 4)      { ksplit = 246; kch = 120; }
    else if (ws_size >= (fixed + (size_t)123 * 64 * N1) * 4) { ksplit = 123; kch = 240; }

    float* ws   = (float*)d_ws;
    float* sigT = ws;                                // 29520 x 64 (transposed)
    float* part = sigT + (long)NPATH * SIGCH;        // ksplit*64*512
    float* z1   = part + (long)ksplit * 64 * N1;     // 64*512
    float* z2   = z1 + 64 * N1;                      // 64*256
    float* out  = (float*)d_out;

    sig_kernel<<<NPATH, 256, 0, stream>>>(x, cw, cb, sigT);
    gemm1_kernel<<<dim3(2, ksplit), 256, 0, stream>>>(sigT, w0, part, kch);
    red1_kernel<<<256, 256, 0, stream>>>(part, b0, z1, ksplit);
    gemm2_kernel<<<256, 256, 0, stream>>>(z1, w1, b1, z2);
    head_kernel<<<64, 64, 0, stream>>>(z2, w2, b2, out);
}